// Round 14
// baseline (216.494 us; speedup 1.0000x reference)
//
#include <hip/hip_runtime.h>
#include <math.h>

#define Nn 50000
#define Ee 400000
#define FSz 256
#define HD_ 512
#define Bb 1024
#define HSZ 2048

// World model (settled R5/R6): ALL float inputs fp32; OUTPUT fp32.
static __device__ __forceinline__ int clampi(int v, int lo, int hi){
    return v < lo ? lo : (v > hi ? hi : v);
}
static __device__ __forceinline__ unsigned short f2bf(float f){
    unsigned int u = __float_as_uint(f);
    unsigned int r = u + 0x7FFFu + ((u >> 16) & 1u);
    return (unsigned short)(r >> 16);
}
static __device__ __forceinline__ float bflo(unsigned int v){ return __uint_as_float(v << 16); }
static __device__ __forceinline__ float bfhi(unsigned int v){ return __uint_as_float(v & 0xFFFF0000u); }

// K1: blocks 0-1562: edge scatter via per-block LDS hash of url (node -> chain
//     of batch slots). blocks 1563-1578: parallel fold attn -> wl,wr [8][256].
__global__ __launch_bounds__(256) void k_scatter(const int* __restrict__ src, const int* __restrict__ dst,
                                                 const int* __restrict__ url,
                                                 int* __restrict__ fill, int* __restrict__ slist,
                                                 const float* __restrict__ W,
                                                 const float* __restrict__ al,
                                                 const float* __restrict__ ar,
                                                 float* __restrict__ wl, float* __restrict__ wr){
    int t = threadIdx.x;
    if(blockIdx.x >= 1563){
        int bi = blockIdx.x - 1563;       // 0..15
        int wv = t >> 6, lane = t & 63;
        #pragma unroll
        for(int r = 0; r < 4; r++){
            int f = bi*16 + wv*4 + r;
            float pl[8], pr[8];
            #pragma unroll
            for(int h = 0; h < 8; h++){
                float w = W[f*512 + h*64 + lane];
                pl[h] = w * al[h*64 + lane];
                pr[h] = w * ar[h*64 + lane];
            }
            #pragma unroll
            for(int h = 0; h < 8; h++){
                #pragma unroll
                for(int m = 32; m >= 1; m >>= 1){
                    pl[h] += __shfl_xor(pl[h], m, 64);
                    pr[h] += __shfl_xor(pr[h], m, 64);
                }
            }
            #pragma unroll
            for(int h = 0; h < 8; h++){
                if(lane == h){ wl[h*256 + f] = pl[h]; wr[h*256 + f] = pr[h]; }
            }
        }
        return;
    }
    __shared__ int key[HSZ];        // node id or -1
    __shared__ int chainhead[HSZ];  // batch-slot chain head or -1
    __shared__ short nxt[Bb];       // next slot with same node (-1 terminal)
    for(int i = t; i < HSZ; i += 256){ key[i] = -1; chainhead[i] = -1; }
    __syncthreads();
    for(int b = t; b < Bb; b += 256){
        int n = clampi(url[b] - 1, 0, Nn - 1);
        int h = n & (HSZ - 1);
        while(true){
            int prev = atomicCAS(&key[h], -1, n);
            if(prev == -1 || prev == n) break;
            h = (h + 1) & (HSZ - 1);
        }
        int old = atomicExch(&chainhead[h], b);
        nxt[b] = (short)old;
    }
    __syncthreads();
    int e = blockIdx.x * 256 + t;
    if(e >= Ee) return;
    int d = dst[e];
    if((unsigned)d >= (unsigned)Nn) return;
    int h = d & (HSZ - 1);
    while(true){
        int k = key[h];
        if(k == -1) return;
        if(k == d) break;
        h = (h + 1) & (HSZ - 1);
    }
    int s = clampi(src[e], 0, Nn - 1);
    for(int b = chainhead[h]; b != -1; b = nxt[b]){
        int pos = atomicAdd(&fill[b], 1);
        if(pos < 64) slist[b*64 + pos] = s;
    }
}

// K3: 2 slots/block, grid 512 (2 blocks/CU — R12's grid 256 starved CUs):
// per-edge el via wave-reduce (weights in registers), softmax, alpha-combine
// (unroll 2 -> 4 gathers in flight), dual GEMV.
__global__ __launch_bounds__(256) void k_gat(const float* __restrict__ features,
                                             const float* __restrict__ Wfc,
                                             const float* __restrict__ Wres,
                                             const float* __restrict__ bias,
                                             const float* __restrict__ wl,   // [8][256] transposed
                                             const float* __restrict__ wr,
                                             const int* __restrict__ url,
                                             const int* __restrict__ fill, const int* __restrict__ slist,
                                             float* __restrict__ gemb){
    int t = threadIdx.x;
    int lane = t & 63, wv = t >> 6;
    int u0 = blockIdx.x * 2;

    __shared__ float cxs[2][8][256];         // 16 KB
    __shared__ float fres[2][256];           //  2 KB
    __shared__ float sew[2][64][8];          //  4 KB
    __shared__ float ser[2][8];
    __shared__ int   sslist[2][64];

    for(int i = t; i < 2*64*8; i += 256) ((float*)sew)[i] = 0.f;

    float4 rwl[8], rwr[8];
    #pragma unroll
    for(int h = 0; h < 8; h++){
        rwl[h] = *(const float4*)&wl[h*256 + 4*lane];
        rwr[h] = *(const float4*)&wr[h*256 + 4*lane];
    }

    int dg[2], nj[2];
    #pragma unroll
    for(int j = 0; j < 2; j++){
        int u = u0 + j;
        dg[j] = min(fill[u], 64);
        nj[j] = clampi(url[u] - 1, 0, Nn - 1);
        if(t < dg[j]) sslist[j][t] = slist[u*64 + t];
        fres[j][t] = features[(size_t)nj[j] * FSz + t];
    }
    __syncthreads();

    // ---- pass A: wave-level dot products; tasks = all edges + 2 er rows
    int c1 = dg[0];
    int total = c1 + dg[1];
    for(int tau = wv; tau < total + 2; tau += 4){
        int j, i, isEr = 0;
        if(tau < c1){ j = 0; i = tau; }
        else if(tau < total){ j = 1; i = tau - c1; }
        else { j = tau - total; i = 0; isEr = 1; }
        int s = isEr ? nj[j] : sslist[j][i];
        float4 x = *(const float4*)(features + (size_t)s * FSz + 4*lane);
        float p[8];
        if(isEr){
            #pragma unroll
            for(int h = 0; h < 8; h++)
                p[h] = x.x*rwr[h].x + x.y*rwr[h].y + x.z*rwr[h].z + x.w*rwr[h].w;
        } else {
            #pragma unroll
            for(int h = 0; h < 8; h++)
                p[h] = x.x*rwl[h].x + x.y*rwl[h].y + x.z*rwl[h].z + x.w*rwl[h].w;
        }
        #pragma unroll
        for(int h = 0; h < 8; h++){
            #pragma unroll
            for(int m = 32; m >= 1; m >>= 1) p[h] += __shfl_xor(p[h], m, 64);
        }
        if(lane == 0){
            if(isEr){
                #pragma unroll
                for(int h = 0; h < 8; h++) ser[j][h] = p[h];
            } else {
                #pragma unroll
                for(int h = 0; h < 8; h++) sew[j][i][h] = p[h];
            }
        }
    }
    __syncthreads();
    // ---- softmax per (slot, head)
    if(t < 16){
        int j = t >> 3, h = t & 7;
        int dgj = dg[j];
        if(dgj > 0){
            float ern = ser[j][h];
            float m = -1e30f;
            for(int i = 0; i < dgj; i++){
                float v = sew[j][i][h] + ern;
                v = v > 0.f ? v : 0.2f * v;
                m = fmaxf(m, v);
            }
            float sum = 0.f;
            for(int i = 0; i < dgj; i++){
                float v = sew[j][i][h] + ern;
                v = v > 0.f ? v : 0.2f * v;
                float w = expf(v - m);
                sum += w;
                sew[j][i][h] = w;
            }
            float inv = 1.0f / fmaxf(sum, 1e-20f);
            for(int i = 0; i < dgj; i++) sew[j][i][h] *= inv;
        }
    }
    __syncthreads();
    // ---- pass B: alpha-combine; 2 slots x unroll 2 -> 4 gathers in flight
    {
        float cx[2][8];
        #pragma unroll
        for(int j = 0; j < 2; j++)
            #pragma unroll
            for(int h = 0; h < 8; h++) cx[j][h] = 0.f;
        int mxd = max(dg[0], dg[1]);
        for(int i = 0; i < mxd; i += 2){
            float x[2][2];
            #pragma unroll
            for(int j = 0; j < 2; j++)
                #pragma unroll
                for(int ii = 0; ii < 2; ii++){
                    int idx = i + ii;
                    int s = (idx < dg[j]) ? sslist[j][idx] : 0;
                    x[j][ii] = features[(size_t)s * FSz + t];
                }
            #pragma unroll
            for(int j = 0; j < 2; j++)
                #pragma unroll
                for(int ii = 0; ii < 2; ii++){
                    int idx = i + ii;
                    const float* av = &sew[j][idx < 64 ? idx : 0][0];
                    float xm = (idx < dg[j]) ? x[j][ii] : 0.f;
                    #pragma unroll
                    for(int h = 0; h < 8; h++) cx[j][h] += av[h] * xm;
                }
        }
        #pragma unroll
        for(int j = 0; j < 2; j++)
            #pragma unroll
            for(int h = 0; h < 8; h++) cxs[j][h][t] = cx[j][h];
    }
    __syncthreads();

    // ---- dual GEMV
    int h = t >> 5;
    int o0 = 2 * t;
    const float2* Wfc2  = (const float2*)Wfc;
    const float2* Wres2 = (const float2*)Wres;
    float a[2][2] = {{0,0},{0,0}};
    for(int f = 0; f < 256; f += 4){
        float2 w0 = Wfc2[(f+0)*256 + t];
        float2 w1 = Wfc2[(f+1)*256 + t];
        float2 w2 = Wfc2[(f+2)*256 + t];
        float2 w3 = Wfc2[(f+3)*256 + t];
        float2 r0 = Wres2[(f+0)*256 + t];
        float2 r1 = Wres2[(f+1)*256 + t];
        float2 r2 = Wres2[(f+2)*256 + t];
        float2 r3 = Wres2[(f+3)*256 + t];
        #pragma unroll
        for(int j = 0; j < 2; j++){
            float4 c = *(const float4*)&cxs[j][h][f];
            float4 x = *(const float4*)&fres[j][f];
            a[j][0] += c.x*w0.x + c.y*w1.x + c.z*w2.x + c.w*w3.x
                     + x.x*r0.x + x.y*r1.x + x.z*r2.x + x.w*r3.x;
            a[j][1] += c.x*w0.y + c.y*w1.y + c.z*w2.y + c.w*w3.y
                     + x.x*r0.y + x.y*r1.y + x.z*r2.y + x.w*r3.y;
        }
    }
    float b0 = bias[o0], b1 = bias[o0 + 1];
    #pragma unroll
    for(int j = 0; j < 2; j++){
        float2* gp = (float2*)(gemb + (size_t)(u0 + j) * HD_);
        gp[t] = make_float2(a[j][0] + b0, a[j][1] + b1);
    }
}

// K4: 512 threads, 2 elems/block, grid 512 -> 16 waves/CU (was 6-8).
// Thread owns ONE column for both elems (half the per-thread VALU chain).
// fc: waves 0-3 own elem 0 k-ranges, waves 4-7 elem 1.
__global__ __launch_bounds__(512, 2) void k_mha(const float* __restrict__ gemb,
                                             const float* __restrict__ lng, const float* __restrict__ lnb,
                                             const float* __restrict__ wq, const float* __restrict__ wk,
                                             const float* __restrict__ wvp, const float* __restrict__ fcw,
                                             const float* __restrict__ fcb, const float* __restrict__ mlg,
                                             const float* __restrict__ mlb, const float* __restrict__ outw,
                                             const float* __restrict__ outb, float* __restrict__ out){
    __shared__ float A[2][512];                // xr -> sc -> yy
    __shared__ float xnF[2][512];              // fp32 LN1 out (residual)
    __shared__ unsigned short xnT[2][512];     // bf16 LN1 out, [d*8+q]
    __shared__ unsigned short qkb[2][8320];    // bf16 q | k ; k-region reused for fp32 partials
    __shared__ float mu8[2][8], rs8[2][8], pooled[2][64];

    int t = threadIdx.x;            // 0..511
    int lane = t & 63, wv = t >> 6; // wv 0..7
    int e0 = blockIdx.x * 2;

    {
        const float* g0 = gemb + (size_t)e0 * HD_;
        const float* g1 = gemb + (size_t)(e0 + 1) * HD_;
        A[0][t] = g0[t];
        A[1][t] = g1[t];
    }
    __syncthreads();
    if(t < 16){
        int ee = t >> 3, q = t & 7;
        float s = 0.f, s2 = 0.f;
        for(int d = 0; d < 64; d++){ float v = A[ee][q*64 + d]; s += v; s2 += v * v; }
        float mu = s * (1.0f/64.0f);
        float var = s2 * (1.0f/64.0f) - mu * mu;
        mu8[ee][q] = mu; rs8[ee][q] = rsqrtf(fmaxf(var, 0.0f) + 1e-6f);
    }
    __syncthreads();
    #pragma unroll
    for(int p = 0; p < 2; p++){
        int i = p*512 + t; int ee = i >> 9, ii = i & 511, q = ii >> 6, d = ii & 63;
        float xv = (A[ee][ii] - mu8[ee][q]) * rs8[ee][q] * lng[d] + lnb[d];
        xnF[ee][ii] = xv;
        xnT[ee][d*8 + q] = f2bf(xv);
    }
    __syncthreads();
    // ---- fused q,k,v projection; thread owns col t for both elems ----
    float aq[2][8], ak[2][8], av[2][8];
    #pragma unroll
    for(int ee = 0; ee < 2; ee++)
        #pragma unroll
        for(int r = 0; r < 8; r++){ aq[ee][r]=0.f; ak[ee][r]=0.f; av[ee][r]=0.f; }
    #pragma unroll 2
    for(int d = 0; d < 64; d++){
        float q0 = wq[d*512 + t];
        float k0 = wk[d*512 + t];
        float v0 = wvp[d*512 + t];
        #pragma unroll
        for(int ee = 0; ee < 2; ee++){
            uint4 xp = *(const uint4*)&xnT[ee][d*8];
            float xv[8] = { bflo(xp.x), bfhi(xp.x), bflo(xp.y), bfhi(xp.y),
                            bflo(xp.z), bfhi(xp.z), bflo(xp.w), bfhi(xp.w) };
            #pragma unroll
            for(int r = 0; r < 8; r++){
                aq[ee][r] += xv[r]*q0;
                ak[ee][r] += xv[r]*k0;
                av[ee][r] += xv[r]*v0;
            }
        }
    }
    #pragma unroll
    for(int ee = 0; ee < 2; ee++)
        #pragma unroll
        for(int qq = 0; qq < 8; qq++){
            qkb[ee][qq*520 + t]        = f2bf(aq[ee][qq]);
            qkb[ee][4160 + qq*520 + t] = f2bf(ak[ee][qq]);
        }
    __syncthreads();
    // ---- scores: 1024 tasks / 512 threads ----
    #pragma unroll
    for(int p = 0; p < 2; p++){
        int i = p*512 + t;
        int ee = i >> 9, idx = i & 511;
        int nh = idx >> 6, qq = (idx >> 3) & 7, kk = idx & 7;
        const unsigned short* qrow = &qkb[ee][qq*520 + nh*64];
        const unsigned short* krow = &qkb[ee][4160 + kk*520 + nh*64];
        float s = 0.f;
        #pragma unroll
        for(int d8 = 0; d8 < 64; d8 += 8){
            uint4 qv = *(const uint4*)&qrow[d8];
            uint4 kv = *(const uint4*)&krow[d8];
            s += bflo(qv.x)*bflo(kv.x) + bfhi(qv.x)*bfhi(kv.x)
               + bflo(qv.y)*bflo(kv.y) + bfhi(qv.y)*bfhi(kv.y)
               + bflo(qv.z)*bflo(kv.z) + bfhi(qv.z)*bfhi(kv.z)
               + bflo(qv.w)*bflo(kv.w) + bfhi(qv.w)*bfhi(kv.w);
        }
        A[ee][idx] = s * 0.125f;
    }
    __syncthreads();
    if(t < 128){
        int ee = t >> 6, row = t & 63;
        float mx = -1e30f;
        #pragma unroll
        for(int k = 0; k < 8; k++) mx = fmaxf(mx, A[ee][row*8 + k]);
        float e[8]; float s = 0.f;
        #pragma unroll
        for(int k = 0; k < 8; k++){ e[k] = expf(A[ee][row*8 + k] - mx); s += e[k]; }
        float inv = 1.0f / s;
        #pragma unroll
        for(int k = 0; k < 8; k++) A[ee][row*8 + k] = e[k] * inv;
    }
    __syncthreads();
    // ---- attn @ v (v in registers) -> ov (bf16) into q regions ----
    {
        int nh = t >> 6;
        #pragma unroll
        for(int ee = 0; ee < 2; ee++){
            #pragma unroll
            for(int qq = 0; qq < 8; qq++){
                const float* s0 = &A[ee][nh*64 + qq*8];
                float4 a0 = *(const float4*)s0, b0 = *(const float4*)(s0 + 4);
                float o0 = a0.x*av[ee][0] + a0.y*av[ee][1] + a0.z*av[ee][2] + a0.w*av[ee][3]
                         + b0.x*av[ee][4] + b0.y*av[ee][5] + b0.z*av[ee][6] + b0.w*av[ee][7];
                qkb[ee][qq*520 + t] = f2bf(o0);
            }
        }
    }
    __syncthreads();
    // ---- fc: wave wv -> elem (wv>>2), k-range ((wv&3)*128) ----
    {
        float* P0 = (float*)&qkb[0][4160];   // 8 KB partials per elem (k regions dead)
        float* P1 = (float*)&qkb[1][4160];
        int ee = wv >> 2;
        int k0r = (wv & 3) * 128;
        int g = lane & 31;
        int qh = lane >> 5;
        float a[4][2] = {{0,0},{0,0},{0,0},{0,0}};
        const float2* fw2 = (const float2*)fcw;   // [512][32] float2
        for(int k = k0r; k < k0r + 128; k += 8){
            float2 f0 = fw2[(k+0)*32 + g];
            float2 f1 = fw2[(k+1)*32 + g];
            float2 f2 = fw2[(k+2)*32 + g];
            float2 f3 = fw2[(k+3)*32 + g];
            float2 f4 = fw2[(k+4)*32 + g];
            float2 f5 = fw2[(k+5)*32 + g];
            float2 f6 = fw2[(k+6)*32 + g];
            float2 f7 = fw2[(k+7)*32 + g];
            #pragma unroll
            for(int jq = 0; jq < 4; jq++){
                int qq = qh*4 + jq;
                uint4 op = *(const uint4*)&qkb[ee][qq*520 + k];
                float x0 = bflo(op.x), x1 = bfhi(op.x), x2 = bflo(op.y), x3 = bfhi(op.y);
                float x4 = bflo(op.z), x5 = bfhi(op.z), x6 = bflo(op.w), x7 = bfhi(op.w);
                a[jq][0] += x0*f0.x + x1*f1.x + x2*f2.x + x3*f3.x + x4*f4.x + x5*f5.x + x6*f6.x + x7*f7.x;
                a[jq][1] += x0*f0.y + x1*f1.y + x2*f2.y + x3*f3.y + x4*f4.y + x5*f5.y + x6*f6.y + x7*f7.y;
            }
        }
        __syncthreads();
        {
            float* P = ee ? P1 : P0;
            #pragma unroll
            for(int jq = 0; jq < 4; jq++){
                int qq = qh*4 + jq;
                *(float2*)&P[(wv & 3)*512 + qq*64 + 2*g] = make_float2(a[jq][0], a[jq][1]);
            }
        }
        __syncthreads();
        #pragma unroll
        for(int p = 0; p < 2; p++){
            int i = p*512 + t;
            int e2 = i >> 9, o = i & 511, dd = o & 63;
            const float* P = e2 ? P1 : P0;
            A[e2][o] = P[o] + P[512 + o] + P[1024 + o] + P[1536 + o] + fcb[dd] + xnF[e2][o];
        }
    }
    __syncthreads();
    if(t < 16){
        int ee = t >> 3, q = t & 7;
        float s = 0.f, s2 = 0.f;
        for(int d = 0; d < 64; d++){ float v = A[ee][q*64 + d]; s += v; s2 += v * v; }
        float mu = s * (1.0f/64.0f);
        float var = s2 * (1.0f/64.0f) - mu * mu;
        mu8[ee][q] = mu; rs8[ee][q] = rsqrtf(fmaxf(var, 0.0f) + 1e-6f);
    }
    __syncthreads();
    if(t < 128){
        int ee = t >> 6, dd = t & 63;
        float g2 = mlg[dd], bb = mlb[dd];
        float s = 0.f;
        #pragma unroll
        for(int qq = 0; qq < 8; qq++)
            s += (A[ee][qq*64 + dd] - mu8[ee][qq]) * rs8[ee][qq] * g2 + bb;
        pooled[ee][dd] = s;
    }
    __syncthreads();
    if(t < 4){
        int ee = t >> 1, c = t & 1;
        float s = outb[c];
        for(int d = 0; d < 64; d++) s += pooled[ee][d] * outw[d*2 + c];
        out[(e0 + ee)*2 + c] = s;
    }
}

extern "C" void kernel_launch(void* const* d_in, const int* in_sizes, int n_in,
                              void* d_out, int out_size, void* d_ws, size_t ws_size,
                              hipStream_t stream){
    (void)in_sizes; (void)n_in; (void)out_size; (void)ws_size;
    const float* features  = (const float*)d_in[0];
    const int*   src       = (const int*)d_in[1];
    const int*   dst       = (const int*)d_in[2];
    const int*   url       = (const int*)d_in[3];
    const float* gat_fc_w  = (const float*)d_in[4];
    const float* attn_l    = (const float*)d_in[5];
    const float* attn_r    = (const float*)d_in[6];
    const float* gat_res_w = (const float*)d_in[7];
    const float* gat_bias  = (const float*)d_in[8];
    const float* ln_g      = (const float*)d_in[9];
    const float* ln_b      = (const float*)d_in[10];
    const float* wq        = (const float*)d_in[11];
    const float* wk        = (const float*)d_in[12];
    const float* wv        = (const float*)d_in[13];
    const float* fc_w      = (const float*)d_in[14];
    const float* fc_b      = (const float*)d_in[15];
    const float* mha_ln_g  = (const float*)d_in[16];
    const float* mha_ln_b  = (const float*)d_in[17];
    const float* out_w     = (const float*)d_in[18];
    const float* out_b     = (const float*)d_in[19];

    char* base = (char*)d_ws;
    size_t cur = 0;
    auto alloc = [&](size_t nbytes) -> void* {
        void* p = base + cur;
        cur = (cur + nbytes + 255) & ~(size_t)255;
        return p;
    };
    float* wl    = (float*)alloc(2048 * sizeof(float));   // transposed [8][256]
    float* wr    = (float*)alloc(2048 * sizeof(float));
    int*   fill  = (int*)alloc(1024 * sizeof(int));
    int*   slist = (int*)alloc((size_t)1024 * 64 * sizeof(int));
    float* gemb  = (float*)alloc((size_t)1024 * 512 * sizeof(float));

    hipMemsetAsync(fill, 0, 1024 * sizeof(int), stream);

    hipLaunchKernelGGL(k_scatter, dim3(1579), dim3(256), 0, stream, src, dst, url, fill, slist,
                       gat_fc_w, attn_l, attn_r, wl, wr);
    hipLaunchKernelGGL(k_gat,     dim3(512),  dim3(256), 0, stream, features, gat_fc_w, gat_res_w, gat_bias,
                       wl, wr, url, fill, slist, gemb);
    hipLaunchKernelGGL(k_mha,     dim3(512),  dim3(512), 0, stream, gemb, ln_g, ln_b,
                       wq, wk, wv, fc_w, fc_b, mha_ln_g, mha_ln_b, out_w, out_b,
                       (float*)d_out);
}

// Round 15
// 203.429 us; speedup vs baseline: 1.0642x; 1.0642x over previous
//
#include <hip/hip_runtime.h>
#include <math.h>

#define Nn 50000
#define Ee 400000
#define FSz 256
#define HD_ 512
#define Bb 1024
#define HSZ 2048

// World model (settled R5/R6): ALL float inputs fp32; OUTPUT fp32.
static __device__ __forceinline__ int clampi(int v, int lo, int hi){
    return v < lo ? lo : (v > hi ? hi : v);
}
static __device__ __forceinline__ unsigned short f2bf(float f){
    unsigned int u = __float_as_uint(f);
    unsigned int r = u + 0x7FFFu + ((u >> 16) & 1u);
    return (unsigned short)(r >> 16);
}
static __device__ __forceinline__ float bflo(unsigned int v){ return __uint_as_float(v << 16); }
static __device__ __forceinline__ float bfhi(unsigned int v){ return __uint_as_float(v & 0xFFFF0000u); }

// K1: blocks 0-1562: edge scatter via per-block LDS hash of url.
//     blocks 1563-1578: parallel fold attn -> wl,wr [8][256].
//     blocks 1579-1610: convert Wfc/Wres to packed bf16 pairs (col 2t|2t+1).
__global__ __launch_bounds__(256) void k_scatter(const int* __restrict__ src, const int* __restrict__ dst,
                                                 const int* __restrict__ url,
                                                 int* __restrict__ fill, int* __restrict__ slist,
                                                 const float* __restrict__ W,
                                                 const float* __restrict__ al,
                                                 const float* __restrict__ ar,
                                                 float* __restrict__ wl, float* __restrict__ wr,
                                                 const float* __restrict__ Wfc,
                                                 const float* __restrict__ Wres,
                                                 unsigned int* __restrict__ wfcb,
                                                 unsigned int* __restrict__ wresb){
    int t = threadIdx.x;
    if(blockIdx.x >= 1579){
        // bf16-pack Wfc and Wres: out[f*256+c] = pack(bf(W[f*512+2c]), bf(W[f*512+2c+1]))
        int bi = blockIdx.x - 1579;           // 0..31
        int m = bi >> 4;                      // 0: Wfc, 1: Wres
        const float2* Sf = (const float2*)(m ? Wres : Wfc);
        unsigned int* D = m ? wresb : wfcb;
        int base = (bi & 15) * 8192;          // 16 blocks x 8192 = 131072 pairs
        #pragma unroll
        for(int i = 0; i < 32; i++){
            int idx = base + i*256 + t;
            float2 v = Sf[idx];               // pair (2c, 2c+1) of row f
            D[idx] = ((unsigned int)f2bf(v.y) << 16) | (unsigned int)f2bf(v.x);
        }
        return;
    }
    if(blockIdx.x >= 1563){
        int bi = blockIdx.x - 1563;       // 0..15
        int wv = t >> 6, lane = t & 63;
        #pragma unroll
        for(int r = 0; r < 4; r++){
            int f = bi*16 + wv*4 + r;
            float pl[8], pr[8];
            #pragma unroll
            for(int h = 0; h < 8; h++){
                float w = W[f*512 + h*64 + lane];
                pl[h] = w * al[h*64 + lane];
                pr[h] = w * ar[h*64 + lane];
            }
            #pragma unroll
            for(int h = 0; h < 8; h++){
                #pragma unroll
                for(int m = 32; m >= 1; m >>= 1){
                    pl[h] += __shfl_xor(pl[h], m, 64);
                    pr[h] += __shfl_xor(pr[h], m, 64);
                }
            }
            #pragma unroll
            for(int h = 0; h < 8; h++){
                if(lane == h){ wl[h*256 + f] = pl[h]; wr[h*256 + f] = pr[h]; }
            }
        }
        return;
    }
    __shared__ int key[HSZ];
    __shared__ int chainhead[HSZ];
    __shared__ short nxt[Bb];
    for(int i = t; i < HSZ; i += 256){ key[i] = -1; chainhead[i] = -1; }
    __syncthreads();
    for(int b = t; b < Bb; b += 256){
        int n = clampi(url[b] - 1, 0, Nn - 1);
        int h = n & (HSZ - 1);
        while(true){
            int prev = atomicCAS(&key[h], -1, n);
            if(prev == -1 || prev == n) break;
            h = (h + 1) & (HSZ - 1);
        }
        int old = atomicExch(&chainhead[h], b);
        nxt[b] = (short)old;
    }
    __syncthreads();
    int e = blockIdx.x * 256 + t;
    if(e >= Ee) return;
    int d = dst[e];
    if((unsigned)d >= (unsigned)Nn) return;
    int h = d & (HSZ - 1);
    while(true){
        int k = key[h];
        if(k == -1) return;
        if(k == d) break;
        h = (h + 1) & (HSZ - 1);
    }
    int s = clampi(src[e], 0, Nn - 1);
    for(int b = chainhead[h]; b != -1; b = nxt[b]){
        int pos = atomicAdd(&fill[b], 1);
        if(pos < 64) slist[b*64 + pos] = s;
    }
}

// K3: 2 slots/block, grid 512. GEMV weights now packed bf16 pairs (halves the
// 1 MB/block L2 weight stream that floored k_gat).
__global__ __launch_bounds__(256) void k_gat(const float* __restrict__ features,
                                             const unsigned int* __restrict__ Wfcb,   // [256][256] bf16 pairs
                                             const unsigned int* __restrict__ Wresb,
                                             const float* __restrict__ bias,
                                             const float* __restrict__ wl,   // [8][256] transposed
                                             const float* __restrict__ wr,
                                             const int* __restrict__ url,
                                             const int* __restrict__ fill, const int* __restrict__ slist,
                                             float* __restrict__ gemb){
    int t = threadIdx.x;
    int lane = t & 63, wv = t >> 6;
    int u0 = blockIdx.x * 2;

    __shared__ float cxs[2][8][256];
    __shared__ float fres[2][256];
    __shared__ float sew[2][64][8];
    __shared__ float ser[2][8];
    __shared__ int   sslist[2][64];

    for(int i = t; i < 2*64*8; i += 256) ((float*)sew)[i] = 0.f;

    float4 rwl[8], rwr[8];
    #pragma unroll
    for(int h = 0; h < 8; h++){
        rwl[h] = *(const float4*)&wl[h*256 + 4*lane];
        rwr[h] = *(const float4*)&wr[h*256 + 4*lane];
    }

    int dg[2], nj[2];
    #pragma unroll
    for(int j = 0; j < 2; j++){
        int u = u0 + j;
        dg[j] = min(fill[u], 64);
        nj[j] = clampi(url[u] - 1, 0, Nn - 1);
        if(t < dg[j]) sslist[j][t] = slist[u*64 + t];
        fres[j][t] = features[(size_t)nj[j] * FSz + t];
    }
    __syncthreads();

    // ---- pass A: wave-level dot products; tasks = all edges + 2 er rows
    int c1 = dg[0];
    int total = c1 + dg[1];
    for(int tau = wv; tau < total + 2; tau += 4){
        int j, i, isEr = 0;
        if(tau < c1){ j = 0; i = tau; }
        else if(tau < total){ j = 1; i = tau - c1; }
        else { j = tau - total; i = 0; isEr = 1; }
        int s = isEr ? nj[j] : sslist[j][i];
        float4 x = *(const float4*)(features + (size_t)s * FSz + 4*lane);
        float p[8];
        if(isEr){
            #pragma unroll
            for(int h = 0; h < 8; h++)
                p[h] = x.x*rwr[h].x + x.y*rwr[h].y + x.z*rwr[h].z + x.w*rwr[h].w;
        } else {
            #pragma unroll
            for(int h = 0; h < 8; h++)
                p[h] = x.x*rwl[h].x + x.y*rwl[h].y + x.z*rwl[h].z + x.w*rwl[h].w;
        }
        #pragma unroll
        for(int h = 0; h < 8; h++){
            #pragma unroll
            for(int m = 32; m >= 1; m >>= 1) p[h] += __shfl_xor(p[h], m, 64);
        }
        if(lane == 0){
            if(isEr){
                #pragma unroll
                for(int h = 0; h < 8; h++) ser[j][h] = p[h];
            } else {
                #pragma unroll
                for(int h = 0; h < 8; h++) sew[j][i][h] = p[h];
            }
        }
    }
    __syncthreads();
    // ---- softmax per (slot, head)
    if(t < 16){
        int j = t >> 3, h = t & 7;
        int dgj = dg[j];
        if(dgj > 0){
            float ern = ser[j][h];
            float m = -1e30f;
            for(int i = 0; i < dgj; i++){
                float v = sew[j][i][h] + ern;
                v = v > 0.f ? v : 0.2f * v;
                m = fmaxf(m, v);
            }
            float sum = 0.f;
            for(int i = 0; i < dgj; i++){
                float v = sew[j][i][h] + ern;
                v = v > 0.f ? v : 0.2f * v;
                float w = expf(v - m);
                sum += w;
                sew[j][i][h] = w;
            }
            float inv = 1.0f / fmaxf(sum, 1e-20f);
            for(int i = 0; i < dgj; i++) sew[j][i][h] *= inv;
        }
    }
    __syncthreads();
    // ---- pass B: alpha-combine; 2 slots x unroll 2 -> 4 gathers in flight
    {
        float cx[2][8];
        #pragma unroll
        for(int j = 0; j < 2; j++)
            #pragma unroll
            for(int h = 0; h < 8; h++) cx[j][h] = 0.f;
        int mxd = max(dg[0], dg[1]);
        for(int i = 0; i < mxd; i += 2){
            float x[2][2];
            #pragma unroll
            for(int j = 0; j < 2; j++)
                #pragma unroll
                for(int ii = 0; ii < 2; ii++){
                    int idx = i + ii;
                    int s = (idx < dg[j]) ? sslist[j][idx] : 0;
                    x[j][ii] = features[(size_t)s * FSz + t];
                }
            #pragma unroll
            for(int j = 0; j < 2; j++)
                #pragma unroll
                for(int ii = 0; ii < 2; ii++){
                    int idx = i + ii;
                    const float* av = &sew[j][idx < 64 ? idx : 0][0];
                    float xm = (idx < dg[j]) ? x[j][ii] : 0.f;
                    #pragma unroll
                    for(int h = 0; h < 8; h++) cx[j][h] += av[h] * xm;
                }
        }
        #pragma unroll
        for(int j = 0; j < 2; j++)
            #pragma unroll
            for(int h = 0; h < 8; h++) cxs[j][h][t] = cx[j][h];
    }
    __syncthreads();

    // ---- dual GEMV, bf16-pair weights (half the L2 bytes)
    int h = t >> 5;
    int o0 = 2 * t;
    float a[2][2] = {{0,0},{0,0}};
    for(int f = 0; f < 256; f += 4){
        unsigned int w0 = Wfcb[(f+0)*256 + t];
        unsigned int w1 = Wfcb[(f+1)*256 + t];
        unsigned int w2 = Wfcb[(f+2)*256 + t];
        unsigned int w3 = Wfcb[(f+3)*256 + t];
        unsigned int r0 = Wresb[(f+0)*256 + t];
        unsigned int r1 = Wresb[(f+1)*256 + t];
        unsigned int r2 = Wresb[(f+2)*256 + t];
        unsigned int r3 = Wresb[(f+3)*256 + t];
        #pragma unroll
        for(int j = 0; j < 2; j++){
            float4 c = *(const float4*)&cxs[j][h][f];
            float4 x = *(const float4*)&fres[j][f];
            a[j][0] += c.x*bflo(w0) + c.y*bflo(w1) + c.z*bflo(w2) + c.w*bflo(w3)
                     + x.x*bflo(r0) + x.y*bflo(r1) + x.z*bflo(r2) + x.w*bflo(r3);
            a[j][1] += c.x*bfhi(w0) + c.y*bfhi(w1) + c.z*bfhi(w2) + c.w*bfhi(w3)
                     + x.x*bfhi(r0) + x.y*bfhi(r1) + x.z*bfhi(r2) + x.w*bfhi(r3);
        }
    }
    float b0 = bias[o0], b1 = bias[o0 + 1];
    #pragma unroll
    for(int j = 0; j < 2; j++){
        float2* gp = (float2*)(gemb + (size_t)(u0 + j) * HD_);
        gp[t] = make_float2(a[j][0] + b0, a[j][1] + b1);
    }
}

// K4: R13's 256-thread 2-elem k_mha — proven 51.4 µs local optimum
// (R14's 512-thread variant regressed to 60: VALUBusy pinned ~52% regardless
// of occupancy; barrier count and per-thread ILP matter more).
__global__ __launch_bounds__(256, 2) void k_mha(const float* __restrict__ gemb,
                                             const float* __restrict__ lng, const float* __restrict__ lnb,
                                             const float* __restrict__ wq, const float* __restrict__ wk,
                                             const float* __restrict__ wvp, const float* __restrict__ fcw,
                                             const float* __restrict__ fcb, const float* __restrict__ mlg,
                                             const float* __restrict__ mlb, const float* __restrict__ outw,
                                             const float* __restrict__ outb, float* __restrict__ out){
    __shared__ float A[2][512];                // xr -> sc -> yy
    __shared__ float xnF[2][512];              // fp32 LN1 out (residual)
    __shared__ unsigned short xnT[2][512];     // bf16 LN1 out, [d*8+q]
    __shared__ unsigned short qkb[2][8320];    // bf16 q | k ; k-region reused for fp32 partials
    __shared__ float mu8[2][8], rs8[2][8], pooled[2][64];

    int t = threadIdx.x;
    int lane = t & 63, wv = t >> 6;
    int e0 = blockIdx.x * 2;

    {
        const float* g0 = gemb + (size_t)e0 * HD_;
        const float* g1 = gemb + (size_t)(e0 + 1) * HD_;
        A[0][t] = g0[t]; A[0][t + 256] = g0[t + 256];
        A[1][t] = g1[t]; A[1][t + 256] = g1[t + 256];
    }
    __syncthreads();
    if(t < 16){
        int ee = t >> 3, q = t & 7;
        float s = 0.f, s2 = 0.f;
        for(int d = 0; d < 64; d++){ float v = A[ee][q*64 + d]; s += v; s2 += v * v; }
        float mu = s * (1.0f/64.0f);
        float var = s2 * (1.0f/64.0f) - mu * mu;
        mu8[ee][q] = mu; rs8[ee][q] = rsqrtf(fmaxf(var, 0.0f) + 1e-6f);
    }
    __syncthreads();
    #pragma unroll
    for(int p = 0; p < 4; p++){
        int i = p*256 + t; int ee = i >> 9, ii = i & 511, q = ii >> 6, d = ii & 63;
        float xv = (A[ee][ii] - mu8[ee][q]) * rs8[ee][q] * lng[d] + lnb[d];
        xnF[ee][ii] = xv;
        xnT[ee][d*8 + q] = f2bf(xv);
    }
    __syncthreads();
    // ---- fused q,k,v projection for BOTH elems; thread owns cols t, t+256 ----
    float aq0[2][8], aq1[2][8], ak0[2][8], ak1[2][8], av0[2][8], av1[2][8];
    #pragma unroll
    for(int ee = 0; ee < 2; ee++)
        #pragma unroll
        for(int r = 0; r < 8; r++){
            aq0[ee][r]=0.f; aq1[ee][r]=0.f; ak0[ee][r]=0.f;
            ak1[ee][r]=0.f; av0[ee][r]=0.f; av1[ee][r]=0.f;
        }
    #pragma unroll 2
    for(int d = 0; d < 64; d++){
        float q0 = wq[d*512 + t],  q1 = wq[d*512 + t + 256];
        float k0 = wk[d*512 + t],  k1 = wk[d*512 + t + 256];
        float v0 = wvp[d*512 + t], v1 = wvp[d*512 + t + 256];
        #pragma unroll
        for(int ee = 0; ee < 2; ee++){
            uint4 xp = *(const uint4*)&xnT[ee][d*8];
            float xv[8] = { bflo(xp.x), bfhi(xp.x), bflo(xp.y), bfhi(xp.y),
                            bflo(xp.z), bfhi(xp.z), bflo(xp.w), bfhi(xp.w) };
            #pragma unroll
            for(int r = 0; r < 8; r++){
                aq0[ee][r] += xv[r]*q0; aq1[ee][r] += xv[r]*q1;
                ak0[ee][r] += xv[r]*k0; ak1[ee][r] += xv[r]*k1;
                av0[ee][r] += xv[r]*v0; av1[ee][r] += xv[r]*v1;
            }
        }
    }
    #pragma unroll
    for(int ee = 0; ee < 2; ee++)
        #pragma unroll
        for(int qq = 0; qq < 8; qq++){
            qkb[ee][qq*520 + t]              = f2bf(aq0[ee][qq]);
            qkb[ee][qq*520 + t + 256]        = f2bf(aq1[ee][qq]);
            qkb[ee][4160 + qq*520 + t]       = f2bf(ak0[ee][qq]);
            qkb[ee][4160 + qq*520 + t + 256] = f2bf(ak1[ee][qq]);
        }
    __syncthreads();
    // ---- scores: 1024 tasks across both elems ----
    #pragma unroll
    for(int p = 0; p < 4; p++){
        int i = p*256 + t;
        int ee = i >> 9, idx = i & 511;
        int nh = idx >> 6, qq = (idx >> 3) & 7, kk = idx & 7;
        const unsigned short* qrow = &qkb[ee][qq*520 + nh*64];
        const unsigned short* krow = &qkb[ee][4160 + kk*520 + nh*64];
        float s = 0.f;
        #pragma unroll
        for(int d8 = 0; d8 < 64; d8 += 8){
            uint4 qv = *(const uint4*)&qrow[d8];
            uint4 kv = *(const uint4*)&krow[d8];
            s += bflo(qv.x)*bflo(kv.x) + bfhi(qv.x)*bfhi(kv.x)
               + bflo(qv.y)*bflo(kv.y) + bfhi(qv.y)*bfhi(kv.y)
               + bflo(qv.z)*bflo(kv.z) + bfhi(qv.z)*bfhi(kv.z)
               + bflo(qv.w)*bflo(kv.w) + bfhi(qv.w)*bfhi(kv.w);
        }
        A[ee][idx] = s * 0.125f;
    }
    __syncthreads();
    if(t < 128){
        int ee = t >> 6, row = t & 63;
        float mx = -1e30f;
        #pragma unroll
        for(int k = 0; k < 8; k++) mx = fmaxf(mx, A[ee][row*8 + k]);
        float e[8]; float s = 0.f;
        #pragma unroll
        for(int k = 0; k < 8; k++){ e[k] = expf(A[ee][row*8 + k] - mx); s += e[k]; }
        float inv = 1.0f / s;
        #pragma unroll
        for(int k = 0; k < 8; k++) A[ee][row*8 + k] = e[k] * inv;
    }
    __syncthreads();
    // ---- attn @ v (v in registers) -> ov (bf16) into q regions ----
    {
        int nh0 = wv;
        #pragma unroll
        for(int ee = 0; ee < 2; ee++){
            #pragma unroll
            for(int qq = 0; qq < 8; qq++){
                const float* s0 = &A[ee][nh0*64 + qq*8];
                const float* s1 = &A[ee][(nh0+4)*64 + qq*8];
                float4 a0 = *(const float4*)s0, b0 = *(const float4*)(s0 + 4);
                float4 a1 = *(const float4*)s1, b1 = *(const float4*)(s1 + 4);
                float o0 = a0.x*av0[ee][0] + a0.y*av0[ee][1] + a0.z*av0[ee][2] + a0.w*av0[ee][3]
                         + b0.x*av0[ee][4] + b0.y*av0[ee][5] + b0.z*av0[ee][6] + b0.w*av0[ee][7];
                float o1 = a1.x*av1[ee][0] + a1.y*av1[ee][1] + a1.z*av1[ee][2] + a1.w*av1[ee][3]
                         + b1.x*av1[ee][4] + b1.y*av1[ee][5] + b1.z*av1[ee][6] + b1.w*av1[ee][7];
                qkb[ee][qq*520 + t]       = f2bf(o0);
                qkb[ee][qq*520 + t + 256] = f2bf(o1);
            }
        }
    }
    __syncthreads();
    // ---- fc wave-split: wave wv owns k-range for BOTH elems (fcw read once) ----
    {
        float* P0 = (float*)&qkb[0][4160];
        float* P1 = (float*)&qkb[1][4160];
        int g = lane & 31;
        int qh = lane >> 5;
        int k0r = wv * 128;
        float a[2][4][2];
        #pragma unroll
        for(int ee = 0; ee < 2; ee++)
            #pragma unroll
            for(int jq = 0; jq < 4; jq++){ a[ee][jq][0] = 0.f; a[ee][jq][1] = 0.f; }
        const float2* fw2 = (const float2*)fcw;   // [512][32] float2
        for(int k = k0r; k < k0r + 128; k += 8){
            float2 f0 = fw2[(k+0)*32 + g];
            float2 f1 = fw2[(k+1)*32 + g];
            float2 f2 = fw2[(k+2)*32 + g];
            float2 f3 = fw2[(k+3)*32 + g];
            float2 f4 = fw2[(k+4)*32 + g];
            float2 f5 = fw2[(k+5)*32 + g];
            float2 f6 = fw2[(k+6)*32 + g];
            float2 f7 = fw2[(k+7)*32 + g];
            #pragma unroll
            for(int ee = 0; ee < 2; ee++){
                #pragma unroll
                for(int jq = 0; jq < 4; jq++){
                    int qq = qh*4 + jq;
                    uint4 op = *(const uint4*)&qkb[ee][qq*520 + k];
                    float x0 = bflo(op.x), x1 = bfhi(op.x), x2 = bflo(op.y), x3 = bfhi(op.y);
                    float x4 = bflo(op.z), x5 = bfhi(op.z), x6 = bflo(op.w), x7 = bfhi(op.w);
                    a[ee][jq][0] += x0*f0.x + x1*f1.x + x2*f2.x + x3*f3.x + x4*f4.x + x5*f5.x + x6*f6.x + x7*f7.x;
                    a[ee][jq][1] += x0*f0.y + x1*f1.y + x2*f2.y + x3*f3.y + x4*f4.y + x5*f5.y + x6*f6.y + x7*f7.y;
                }
            }
        }
        __syncthreads();
        #pragma unroll
        for(int jq = 0; jq < 4; jq++){
            int qq = qh*4 + jq;
            *(float2*)&P0[wv*512 + qq*64 + 2*g] = make_float2(a[0][jq][0], a[0][jq][1]);
            *(float2*)&P1[wv*512 + qq*64 + 2*g] = make_float2(a[1][jq][0], a[1][jq][1]);
        }
        __syncthreads();
        #pragma unroll
        for(int p = 0; p < 4; p++){
            int i = p*256 + t;
            int ee = i >> 9, o = i & 511, dd = o & 63;
            const float* P = ee ? P1 : P0;
            A[ee][o] = P[o] + P[512 + o] + P[1024 + o] + P[1536 + o] + fcb[dd] + xnF[ee][o];
        }
    }
    __syncthreads();
    if(t < 16){
        int ee = t >> 3, q = t & 7;
        float s = 0.f, s2 = 0.f;
        for(int d = 0; d < 64; d++){ float v = A[ee][q*64 + d]; s += v; s2 += v * v; }
        float mu = s * (1.0f/64.0f);
        float var = s2 * (1.0f/64.0f) - mu * mu;
        mu8[ee][q] = mu; rs8[ee][q] = rsqrtf(fmaxf(var, 0.0f) + 1e-6f);
    }
    __syncthreads();
    if(t < 128){
        int ee = t >> 6, dd = t & 63;
        float g2 = mlg[dd], bb = mlb[dd];
        float s = 0.f;
        #pragma unroll
        for(int qq = 0; qq < 8; qq++)
            s += (A[ee][qq*64 + dd] - mu8[ee][qq]) * rs8[ee][qq] * g2 + bb;
        pooled[ee][dd] = s;
    }
    __syncthreads();
    if(t < 4){
        int ee = t >> 1, c = t & 1;
        float s = outb[c];
        for(int d = 0; d < 64; d++) s += pooled[ee][d] * outw[d*2 + c];
        out[(e0 + ee)*2 + c] = s;
    }
}

extern "C" void kernel_launch(void* const* d_in, const int* in_sizes, int n_in,
                              void* d_out, int out_size, void* d_ws, size_t ws_size,
                              hipStream_t stream){
    (void)in_sizes; (void)n_in; (void)out_size; (void)ws_size;
    const float* features  = (const float*)d_in[0];
    const int*   src       = (const int*)d_in[1];
    const int*   dst       = (const int*)d_in[2];
    const int*   url       = (const int*)d_in[3];
    const float* gat_fc_w  = (const float*)d_in[4];
    const float* attn_l    = (const float*)d_in[5];
    const float* attn_r    = (const float*)d_in[6];
    const float* gat_res_w = (const float*)d_in[7];
    const float* gat_bias  = (const float*)d_in[8];
    const float* ln_g      = (const float*)d_in[9];
    const float* ln_b      = (const float*)d_in[10];
    const float* wq        = (const float*)d_in[11];
    const float* wk        = (const float*)d_in[12];
    const float* wv        = (const float*)d_in[13];
    const float* fc_w      = (const float*)d_in[14];
    const float* fc_b      = (const float*)d_in[15];
    const float* mha_ln_g  = (const float*)d_in[16];
    const float* mha_ln_b  = (const float*)d_in[17];
    const float* out_w     = (const float*)d_in[18];
    const float* out_b     = (const float*)d_in[19];

    char* base = (char*)d_ws;
    size_t cur = 0;
    auto alloc = [&](size_t nbytes) -> void* {
        void* p = base + cur;
        cur = (cur + nbytes + 255) & ~(size_t)255;
        return p;
    };
    float*        wl    = (float*)alloc(2048 * sizeof(float));   // transposed [8][256]
    float*        wr    = (float*)alloc(2048 * sizeof(float));
    int*          fill  = (int*)alloc(1024 * sizeof(int));
    int*          slist = (int*)alloc((size_t)1024 * 64 * sizeof(int));
    float*        gemb  = (float*)alloc((size_t)1024 * 512 * sizeof(float));
    unsigned int* wfcb  = (unsigned int*)alloc((size_t)256 * 512 * sizeof(unsigned short));
    unsigned int* wresb = (unsigned int*)alloc((size_t)256 * 512 * sizeof(unsigned short));

    hipMemsetAsync(fill, 0, 1024 * sizeof(int), stream);

    hipLaunchKernelGGL(k_scatter, dim3(1611), dim3(256), 0, stream, src, dst, url, fill, slist,
                       gat_fc_w, attn_l, attn_r, wl, wr, gat_fc_w, gat_res_w, wfcb, wresb);
    hipLaunchKernelGGL(k_gat,     dim3(512),  dim3(256), 0, stream, features, wfcb, wresb, gat_bias,
                       wl, wr, url, fill, slist, gemb);
    hipLaunchKernelGGL(k_mha,     dim3(512),  dim3(256), 0, stream, gemb, ln_g, ln_b,
                       wq, wk, wv, fc_w, fc_b, mha_ln_g, mha_ln_b, out_w, out_b,
                       (float*)d_out);
}